// Round 12
// baseline (135.004 us; speedup 1.0000x reference)
//
#include <hip/hip_runtime.h>
#include <hip/hip_fp16.h>

#define N_NODES 50000
#define DIM 64
#define PB 98           // parent buckets = ceil(N/512); bucket = dst >> 9
#define CAP 8960        // per-parent capacity (mean 8163, sd ~90 -> +8.8 sd)
#define EB 6400         // edges per partition block -> runs of ~65 edges/bucket
#define NB 782          // fused blocks = ceil(N/64), 64 nodes each
#define SCAP 1408       // per-64-node-block LDS edge cap (mean 1023, +12 sd)
#define PLW 68          // pooled LDS row stride in floats (+4: bank spread)

typedef _Float16 half8 __attribute__((ext_vector_type(8)));
typedef _Float16 half4v __attribute__((ext_vector_type(4)));
typedef float floatx4 __attribute__((ext_vector_type(4)));

// Workspace byte offsets (16B-aligned).
#define WS_CURSOR  0                          // PB ints (1 KB reserved)
#define WS_COARSE  1024                       // PB*CAP uint = 3,512,320
#define WS_XH      (WS_COARSE + 3512320)      // N*DIM f16 = 6,400,000
#define WS_WT      (WS_XH + 6400000)          // DIM*DIM f16 = 8,192

// ---------------------------------------------------------------------------
// Prep (merged): blocks [0,pa) partition edges into 98 parent buckets
// (two-pass: hist, reserve, scatter; 6400 edges/block -> ~65-edge = 261 B
// contiguous runs per bucket = full-line write-combining).  Blocks
// [pa, pa+3125): x -> fp16.  Last block: W^T fp16.  Edge packed as
// (src<<9)|(dst&511) (src<2^16 -> 25 bits).
// ---------------------------------------------------------------------------
__global__ void __launch_bounds__(256) prep_kernel(
        const float* __restrict__ x, const float* __restrict__ W,
        const int* __restrict__ edge_src, const int* __restrict__ edge_dst,
        int* __restrict__ cursor, unsigned int* __restrict__ coarse,
        _Float16* __restrict__ xh, _Float16* __restrict__ wt,
        int E, int pa) {
    int b = blockIdx.x, t = threadIdx.x;
    if (b < pa) {
        __shared__ int lhist[PB];
        __shared__ int lbase[PB];
        if (t < PB) lhist[t] = 0;
        __syncthreads();

        int base = b * EB;
        int end = base + EB; if (end > E) end = E;

        for (int i = base + t; i < end; i += 256) {
            atomicAdd(&lhist[edge_dst[i] >> 9], 1);
        }
        __syncthreads();
        if (t < PB) {
            lbase[t] = atomicAdd(&cursor[t], lhist[t]);
            lhist[t] = 0;
        }
        __syncthreads();
        for (int i = base + t; i < end; i += 256) {
            int s = edge_src[i];
            int d = edge_dst[i];
            int bk = d >> 9;
            int r = atomicAdd(&lhist[bk], 1);
            coarse[(size_t)bk * CAP + lbase[bk] + r] =
                ((unsigned int)s << 9) | (unsigned int)(d & 511);
        }
    } else if (b < pa + 3125) {
        int i = (b - pa) * 256 + t;           // one float4 per thread
        float4 v = reinterpret_cast<const float4*>(x)[i];
        half4v h = { (_Float16)v.x, (_Float16)v.y, (_Float16)v.z, (_Float16)v.w };
        reinterpret_cast<half4v*>(xh)[i] = h;
    } else {
        #pragma unroll
        for (int i = 0; i < 16; ++i) {        // W^T: wt[n*64+k] = W[k*64+n]
            int idx = t * 16 + i;
            int n = idx >> 6, k = idx & 63;
            wt[idx] = (_Float16)W[k * DIM + n];
        }
    }
}

// ---------------------------------------------------------------------------
// Fused sort + gather + project.  One 256-thread block per 64 nodes
// (grid 782).  Block b filters its 1/8 window of parent bucket b>>3:
//  1. 64-bin LDS hist + wave shfl-scan + scatter into sedges (LDS int
//     atomics only; parent list is L2-hot, shared by 8 blocks).
//  2. 32 groups x 8 lanes, 2 nodes/group: broadcast ds_read of edge ids,
//     half8 fp16 gather, EIGHT edges in flight (deg~16 -> 2 latency rounds),
//     fp32 register accumulate + fp32 residual, one ds_write per row chunk
//     into the stride-68 fp32 LDS tile.
//  3. 4 waves x 16 nodes: in-register fp32->f16 A-frags from the tile,
//     B-frags contiguous from W^T, 2x mfma_f32_16x16x32_f16 per N-tile,
//     fused bias + /deg + ReLU -> out.
// ---------------------------------------------------------------------------
__global__ void __launch_bounds__(256) fused_kernel(
        const float* __restrict__ x,
        const _Float16* __restrict__ xh,
        const _Float16* __restrict__ wt,
        const float* __restrict__ bias,
        const float* __restrict__ deg,
        const int* __restrict__ cursor,
        const unsigned int* __restrict__ coarse,
        float* __restrict__ out) {
    __shared__ unsigned int sedges[SCAP];
    __shared__ float pl[64 * PLW];
    __shared__ int hist[64];
    __shared__ int excl[64];
    __shared__ int cur[64];

    int t = threadIdx.x;
    int b = blockIdx.x;
    int pb = b >> 3;                       // parent bucket (512 nodes)
    int sub = b & 7;                       // our 64-node window within it
    int nb = b * 64;                       // global node base
    int cnt = cursor[pb];
    const unsigned int* cbk = coarse + (size_t)pb * CAP;

    // --- 1a. histogram over our 64 local bins ---
    if (t < 64) hist[t] = 0;
    __syncthreads();
    for (int i = t; i < cnt; i += 256) {
        unsigned int e = cbk[i];
        int loc = (int)(e & 511u);
        if ((loc >> 6) == sub) atomicAdd(&hist[loc & 63], 1);
    }
    __syncthreads();

    // --- 1b. wave shfl-scan (threads 0..63 = wave 0) ---
    if (t < 64) {
        int v = hist[t];
        int s = v;
        #pragma unroll
        for (int off = 1; off < 64; off <<= 1) {
            int u = __shfl_up(s, off);
            if (t >= off) s += u;
        }
        excl[t] = s - v;
        cur[t]  = s - v;
    }
    __syncthreads();

    // --- 1c. scatter src ids into locally-sorted order ---
    for (int i = t; i < cnt; i += 256) {
        unsigned int e = cbk[i];
        int loc = (int)(e & 511u);
        if ((loc >> 6) == sub) {
            int p = atomicAdd(&cur[loc & 63], 1);
            sedges[p] = e >> 9;
        }
    }
    __syncthreads();

    // --- 2. gather: 32 groups of 8 lanes, 2 nodes per group, 8 in flight ---
    int g = t >> 3;          // group 0..31
    int c = t & 7;           // half8 chunk within the 64-half row
    #pragma unroll
    for (int pass = 0; pass < 2; ++pass) {
        int loc = g + pass * 32;
        int node = nb + loc;
        float acc[8];
        #pragma unroll
        for (int j = 0; j < 8; ++j) acc[j] = 0.f;
        int off = excl[loc];
        int ct = (node < N_NODES) ? hist[loc] : 0;
        int k = 0;
        for (; k + 8 <= ct; k += 8) {       // 8 edges in flight
            int sid[8];
            #pragma unroll
            for (int u = 0; u < 8; ++u) sid[u] = (int)sedges[off + k + u];
            half8 v[8];
            #pragma unroll
            for (int u = 0; u < 8; ++u)
                v[u] = *reinterpret_cast<const half8*>(xh + (size_t)sid[u] * DIM + c * 8);
            #pragma unroll
            for (int u = 0; u < 8; ++u)
                #pragma unroll
                for (int j = 0; j < 8; ++j) acc[j] += (float)v[u][j];
        }
        for (; k < ct; ++k) {
            int s0 = (int)sedges[off + k];
            half8 v0 = *reinterpret_cast<const half8*>(xh + (size_t)s0 * DIM + c * 8);
            #pragma unroll
            for (int j = 0; j < 8; ++j) acc[j] += (float)v0[j];
        }
        if (node < N_NODES) {
            const float4 r0 = *reinterpret_cast<const float4*>(
                x + (size_t)node * DIM + c * 8);
            const float4 r1 = *reinterpret_cast<const float4*>(
                x + (size_t)node * DIM + c * 8 + 4);
            float* p = &pl[loc * PLW + c * 8];
            p[0] = acc[0] + r0.x; p[1] = acc[1] + r0.y;
            p[2] = acc[2] + r0.z; p[3] = acc[3] + r0.w;
            p[4] = acc[4] + r1.x; p[5] = acc[5] + r1.y;
            p[6] = acc[6] + r1.z; p[7] = acc[7] + r1.w;
        }
    }
    __syncthreads();

    // --- 3. MFMA projection: wave wv handles nodes lbase..lbase+15 ---
    int wv = t >> 6;
    int lane = t & 63;
    int m = lane & 15;
    int q = lane >> 4;
    int lbase = wv * 16;

    const float* ap = &pl[(lbase + m) * PLW];
    half8 a0, a1;
    #pragma unroll
    for (int j = 0; j < 8; ++j) a0[j] = (_Float16)ap[q * 8 + j];
    #pragma unroll
    for (int j = 0; j < 8; ++j) a1[j] = (_Float16)ap[32 + q * 8 + j];

    floatx4 acc4[4];
    #pragma unroll
    for (int tt = 0; tt < 4; ++tt) {
        half8 b0 = *reinterpret_cast<const half8*>(wt + (size_t)(tt * 16 + m) * DIM + q * 8);
        half8 b1 = *reinterpret_cast<const half8*>(wt + (size_t)(tt * 16 + m) * DIM + q * 8 + 32);
        floatx4 cfrag = {0.f, 0.f, 0.f, 0.f};
        cfrag = __builtin_amdgcn_mfma_f32_16x16x32_f16(a0, b0, cfrag, 0, 0, 0);
        cfrag = __builtin_amdgcn_mfma_f32_16x16x32_f16(a1, b1, cfrag, 0, 0, 0);
        acc4[tt] = cfrag;
    }

    #pragma unroll
    for (int r = 0; r < 4; ++r) {
        int row = q * 4 + r;
        int node = nb + lbase + row;
        if (node < N_NODES) {
            float inv = 1.0f / deg[node];
            #pragma unroll
            for (int tt = 0; tt < 4; ++tt) {
                float v = (acc4[tt][r] + bias[tt * 16 + m]) * inv;
                out[(size_t)node * DIM + tt * 16 + m] = fmaxf(v, 0.f);
            }
        }
    }
}

extern "C" void kernel_launch(void* const* d_in, const int* in_sizes, int n_in,
                              void* d_out, int out_size, void* d_ws, size_t ws_size,
                              hipStream_t stream) {
    const float* x        = (const float*)d_in[0];
    const float* weight   = (const float*)d_in[1];
    const float* bias     = (const float*)d_in[2];
    const float* node_deg = (const float*)d_in[3];
    const int*   edge_src = (const int*)d_in[4];
    const int*   edge_dst = (const int*)d_in[5];
    float* out = (float*)d_out;
    const int E = in_sizes[4];

    char* ws = (char*)d_ws;
    int*          cursor = (int*)(ws + WS_CURSOR);
    unsigned int* coarse = (unsigned int*)(ws + WS_COARSE);
    _Float16*     xh     = (_Float16*)(ws + WS_XH);
    _Float16*     wt     = (_Float16*)(ws + WS_WT);

    hipMemsetAsync(cursor, 0, PB * sizeof(int), stream);

    int pa = (E + EB - 1) / EB;               // 125 partition blocks
    prep_kernel<<<pa + 3125 + 1, 256, 0, stream>>>(
        x, weight, edge_src, edge_dst, cursor, coarse, xh, wt, E, pa);

    fused_kernel<<<NB, 256, 0, stream>>>(
        x, xh, wt, bias, node_deg, cursor, coarse, out);
}

// Round 13
// 119.980 us; speedup vs baseline: 1.1252x; 1.1252x over previous
//
#include <hip/hip_runtime.h>
#include <hip/hip_fp16.h>

#define N_NODES 50000
#define DIM 64
#define CB 391          // coarse buckets = ceil(N/128); bucket = dst >> 7
#define CAP 2560        // per-bucket capacity (mean 2046, sd ~45 -> +11 sd)
#define EB 6400         // edges per partition block -> ~16-edge runs/bucket
#define SCAP 1408       // per-half-bucket LDS edge cap (mean 1023, +12 sd)
#define PLW 68          // pooled LDS row stride in floats (+4: bank spread)

typedef _Float16 half8 __attribute__((ext_vector_type(8)));
typedef _Float16 half4v __attribute__((ext_vector_type(4)));
typedef float floatx4 __attribute__((ext_vector_type(4)));

// Workspace byte offsets (16B-aligned).
#define WS_CURSOR  0                          // CB ints (2 KB reserved)
#define WS_COARSE  2048                       // CB*CAP uint = 4,003,840
#define WS_XH      (WS_COARSE + 4003840)      // N*DIM f16 = 6,400,000
#define WS_WT      (WS_XH + 6400000)          // DIM*DIM f16 = 8,192

// ---------------------------------------------------------------------------
// Prep (merged, == R9): blocks [0,pa) partition edges into 391 buckets
// (two-pass: hist, reserve, scatter; 6400 edges/block -> ~16-edge = 64 B
// runs per bucket).  Blocks [pa, pa+3125): x -> fp16.  Last: W^T fp16.
// Edge packed as (src<<7)|(dst&127).
// ---------------------------------------------------------------------------
__global__ void __launch_bounds__(256) prep_kernel(
        const float* __restrict__ x, const float* __restrict__ W,
        const int* __restrict__ edge_src, const int* __restrict__ edge_dst,
        int* __restrict__ cursor, unsigned int* __restrict__ coarse,
        _Float16* __restrict__ xh, _Float16* __restrict__ wt,
        int E, int pa) {
    int b = blockIdx.x, t = threadIdx.x;
    if (b < pa) {
        __shared__ int lhist[CB];
        __shared__ int lbase[CB];
        for (int i = t; i < CB; i += 256) lhist[i] = 0;
        __syncthreads();

        int base = b * EB;
        int end = base + EB; if (end > E) end = E;

        for (int i = base + t; i < end; i += 256) {
            atomicAdd(&lhist[edge_dst[i] >> 7], 1);
        }
        __syncthreads();
        for (int i = t; i < CB; i += 256) {
            lbase[i] = atomicAdd(&cursor[i], lhist[i]);
            lhist[i] = 0;
        }
        __syncthreads();
        for (int i = base + t; i < end; i += 256) {
            int s = edge_src[i];
            int d = edge_dst[i];
            int bk = d >> 7;
            int r = atomicAdd(&lhist[bk], 1);
            coarse[(size_t)bk * CAP + lbase[bk] + r] =
                ((unsigned int)s << 7) | (unsigned int)(d & 127);
        }
    } else if (b < pa + 3125) {
        int i = (b - pa) * 256 + t;           // one float4 per thread
        float4 v = reinterpret_cast<const float4*>(x)[i];
        half4v h = { (_Float16)v.x, (_Float16)v.y, (_Float16)v.z, (_Float16)v.w };
        reinterpret_cast<half4v*>(xh)[i] = h;
    } else {
        #pragma unroll
        for (int i = 0; i < 16; ++i) {        // W^T: wt[n*64+k] = W[k*64+n]
            int idx = t * 16 + i;
            int n = idx >> 6, k = idx & 63;
            wt[idx] = (_Float16)W[k * DIM + n];
        }
    }
}

// ---------------------------------------------------------------------------
// Fused sort + gather + project.  Grid 784; block b handles half
// half=(b>>3)&1 of bucket (b>>4)*8+(b&7).  The sibling pair is (b, b^8):
// same XCD under round-robin dispatch -> the bucket's edge list is fetched
// into one XCD L2 once, shared by both halves.  bucket 391 (2 blocks) idle.
//  1. Filter bucket list to our 64 nodes: LDS hist + wave shfl-scan +
//     scatter into sedges (LDS int atomics only; 16 scan iterations).
//  2. 32 groups x 8 lanes, 2 nodes/group: 8 edges in flight (deg~16 -> 2
//     latency rounds), half8 fp16 gather, fp32 register accumulate,
//     residual from xh (L2-hot; saves the 12.8 MB fp32 x fetch),
//     one ds_write per row chunk into the stride-68 fp32 tile.
//  3. 4 waves x 16 nodes: fp32->f16 A-frags from the tile, B-frags from
//     W^T, 2x mfma_f32_16x16x32_f16 per N-tile, bias + /deg + ReLU -> out.
// ---------------------------------------------------------------------------
__global__ void __launch_bounds__(256) fused_kernel(
        const _Float16* __restrict__ xh,
        const _Float16* __restrict__ wt,
        const float* __restrict__ bias,
        const float* __restrict__ deg,
        const int* __restrict__ cursor,
        const unsigned int* __restrict__ coarse,
        float* __restrict__ out) {
    __shared__ unsigned int sedges[SCAP];
    __shared__ float pl[64 * PLW];
    __shared__ int hist[64];
    __shared__ int excl[64];
    __shared__ int cur[64];

    int t = threadIdx.x;
    int b = blockIdx.x;
    int bucket = (b >> 4) * 8 + (b & 7);   // pair (b, b^8) -> same bucket+XCD
    int half = (b >> 3) & 1;
    if (bucket >= CB) return;              // block-uniform early-out
    int nb = bucket * 128 + half * 64;     // global node base for this block
    int cnt = cursor[bucket];
    const unsigned int* cbk = coarse + (size_t)bucket * CAP;

    // --- 1a. histogram over our 64 local bins ---
    if (t < 64) hist[t] = 0;
    __syncthreads();
    for (int i = t; i < cnt; i += 256) {
        unsigned int e = cbk[i];
        int loc = (int)(e & 127u);
        if ((loc >> 6) == half) atomicAdd(&hist[loc & 63], 1);
    }
    __syncthreads();

    // --- 1b. wave shfl-scan (threads 0..63 = wave 0) ---
    if (t < 64) {
        int v = hist[t];
        int s = v;
        #pragma unroll
        for (int off = 1; off < 64; off <<= 1) {
            int u = __shfl_up(s, off);
            if (t >= off) s += u;
        }
        excl[t] = s - v;
        cur[t]  = s - v;
    }
    __syncthreads();

    // --- 1c. scatter src ids into locally-sorted order ---
    for (int i = t; i < cnt; i += 256) {
        unsigned int e = cbk[i];
        int loc = (int)(e & 127u);
        if ((loc >> 6) == half) {
            int p = atomicAdd(&cur[loc & 63], 1);
            sedges[p] = e >> 7;
        }
    }
    __syncthreads();

    // --- 2. gather: 32 groups of 8 lanes, 2 nodes per group, 8 in flight ---
    int g = t >> 3;          // group 0..31
    int c = t & 7;           // half8 chunk within the 64-half row
    #pragma unroll
    for (int pass = 0; pass < 2; ++pass) {
        int loc = g + pass * 32;
        int node = nb + loc;
        float acc[8];
        #pragma unroll
        for (int j = 0; j < 8; ++j) acc[j] = 0.f;
        int off = excl[loc];
        int ct = (node < N_NODES) ? hist[loc] : 0;
        int k = 0;
        for (; k + 8 <= ct; k += 8) {       // 8 edges in flight
            int sid[8];
            #pragma unroll
            for (int u = 0; u < 8; ++u) sid[u] = (int)sedges[off + k + u];
            half8 v[8];
            #pragma unroll
            for (int u = 0; u < 8; ++u)
                v[u] = *reinterpret_cast<const half8*>(xh + (size_t)sid[u] * DIM + c * 8);
            #pragma unroll
            for (int u = 0; u < 8; ++u) {
                #pragma unroll
                for (int j = 0; j < 8; ++j) acc[j] += (float)v[u][j];
            }
        }
        for (; k + 4 <= ct; k += 4) {       // 4-wide tail
            int sid[4];
            #pragma unroll
            for (int u = 0; u < 4; ++u) sid[u] = (int)sedges[off + k + u];
            half8 v[4];
            #pragma unroll
            for (int u = 0; u < 4; ++u)
                v[u] = *reinterpret_cast<const half8*>(xh + (size_t)sid[u] * DIM + c * 8);
            #pragma unroll
            for (int u = 0; u < 4; ++u) {
                #pragma unroll
                for (int j = 0; j < 8; ++j) acc[j] += (float)v[u][j];
            }
        }
        for (; k < ct; ++k) {
            int s0 = (int)sedges[off + k];
            half8 v0 = *reinterpret_cast<const half8*>(xh + (size_t)s0 * DIM + c * 8);
            #pragma unroll
            for (int j = 0; j < 8; ++j) acc[j] += (float)v0[j];
        }
        if (node < N_NODES) {
            // Residual from xh: L2-hot, replaces the 12.8 MB fp32 x fetch.
            half8 r = *reinterpret_cast<const half8*>(
                xh + (size_t)node * DIM + c * 8);
            float* p = &pl[loc * PLW + c * 8];
            #pragma unroll
            for (int j = 0; j < 8; ++j) p[j] = acc[j] + (float)r[j];
        }
    }
    __syncthreads();

    // --- 3. MFMA projection: wave wv handles nodes lbase..lbase+15 ---
    int wv = t >> 6;
    int lane = t & 63;
    int m = lane & 15;
    int q = lane >> 4;
    int lbase = wv * 16;

    const float* ap = &pl[(lbase + m) * PLW];
    half8 a0, a1;
    #pragma unroll
    for (int j = 0; j < 8; ++j) a0[j] = (_Float16)ap[q * 8 + j];
    #pragma unroll
    for (int j = 0; j < 8; ++j) a1[j] = (_Float16)ap[32 + q * 8 + j];

    floatx4 acc4[4];
    #pragma unroll
    for (int tt = 0; tt < 4; ++tt) {
        half8 b0 = *reinterpret_cast<const half8*>(wt + (size_t)(tt * 16 + m) * DIM + q * 8);
        half8 b1 = *reinterpret_cast<const half8*>(wt + (size_t)(tt * 16 + m) * DIM + q * 8 + 32);
        floatx4 cfrag = {0.f, 0.f, 0.f, 0.f};
        cfrag = __builtin_amdgcn_mfma_f32_16x16x32_f16(a0, b0, cfrag, 0, 0, 0);
        cfrag = __builtin_amdgcn_mfma_f32_16x16x32_f16(a1, b1, cfrag, 0, 0, 0);
        acc4[tt] = cfrag;
    }

    #pragma unroll
    for (int r = 0; r < 4; ++r) {
        int row = q * 4 + r;
        int node = nb + lbase + row;
        if (node < N_NODES) {
            float inv = 1.0f / deg[node];
            #pragma unroll
            for (int tt = 0; tt < 4; ++tt) {
                float v = (acc4[tt][r] + bias[tt * 16 + m]) * inv;
                out[(size_t)node * DIM + tt * 16 + m] = fmaxf(v, 0.f);
            }
        }
    }
}

extern "C" void kernel_launch(void* const* d_in, const int* in_sizes, int n_in,
                              void* d_out, int out_size, void* d_ws, size_t ws_size,
                              hipStream_t stream) {
    const float* x        = (const float*)d_in[0];
    const float* weight   = (const float*)d_in[1];
    const float* bias     = (const float*)d_in[2];
    const float* node_deg = (const float*)d_in[3];
    const int*   edge_src = (const int*)d_in[4];
    const int*   edge_dst = (const int*)d_in[5];
    float* out = (float*)d_out;
    const int E = in_sizes[4];

    char* ws = (char*)d_ws;
    int*          cursor = (int*)(ws + WS_CURSOR);
    unsigned int* coarse = (unsigned int*)(ws + WS_COARSE);
    _Float16*     xh     = (_Float16*)(ws + WS_XH);
    _Float16*     wt     = (_Float16*)(ws + WS_WT);

    hipMemsetAsync(cursor, 0, CB * sizeof(int), stream);

    int pa = (E + EB - 1) / EB;               // 125 partition blocks
    prep_kernel<<<pa + 3125 + 1, 256, 0, stream>>>(
        x, weight, edge_src, edge_dst, cursor, coarse, xh, wt, E, pa);

    fused_kernel<<<784, 256, 0, stream>>>(
        xh, wt, bias, node_deg, cursor, coarse, out);
}

// Round 14
// 111.969 us; speedup vs baseline: 1.2057x; 1.0715x over previous
//
#include <hip/hip_runtime.h>
#include <hip/hip_fp16.h>

#define N_NODES 50000
#define DIM 64
#define CB 391          // coarse buckets = ceil(N/128); bucket = dst >> 7
#define CAP 2560        // per-bucket capacity (mean 2046, sd ~45 -> +11 sd)
#define EPT 12          // edges per thread in partition (register-staged)
#define EB (512 * EPT)  // 6144 edges per partition block -> 131 blocks
#define BINCAP 64       // per-node LDS edge slots (deg: mean 16 sd 4 -> z=12)
#define PLW 68          // pooled LDS row stride in floats (+4: bank spread)

typedef _Float16 half8 __attribute__((ext_vector_type(8)));
typedef _Float16 half4v __attribute__((ext_vector_type(4)));
typedef float floatx4 __attribute__((ext_vector_type(4)));

// Workspace byte offsets (16B-aligned).
#define WS_CURSOR  0                          // CB ints (2 KB reserved)
#define WS_COARSE  2048                       // CB*CAP uint = 4,003,840
#define WS_XH      (WS_COARSE + 4003840)      // N*DIM f16 = 6,400,000
#define WS_WT      (WS_XH + 6400000)          // DIM*DIM f16 = 8,192

// ---------------------------------------------------------------------------
// Prep (merged, 512 thr): blocks [0,pa): SINGLE-PASS partition — edges are
// staged in registers (EPT=12/thread), so src/dst are read exactly once;
// hist -> reserve -> scatter all from registers.  131 blocks spread over
// 256 CUs (vs R12's 125 two-pass blocks).  Blocks [pa, pa+1563): x -> fp16.
// Last block: W^T fp16.  Edge packed as (src<<7)|(dst&127).
// ---------------------------------------------------------------------------
__global__ void __launch_bounds__(512) prep_kernel(
        const float* __restrict__ x, const float* __restrict__ W,
        const int* __restrict__ edge_src, const int* __restrict__ edge_dst,
        int* __restrict__ cursor, unsigned int* __restrict__ coarse,
        _Float16* __restrict__ xh, _Float16* __restrict__ wt,
        int E, int pa) {
    int b = blockIdx.x, t = threadIdx.x;
    if (b < pa) {
        __shared__ int lhist[CB];
        __shared__ int lbase[CB];
        for (int i = t; i < CB; i += 512) lhist[i] = 0;
        __syncthreads();

        int base = b * EB;
        unsigned int pk[EPT];
        int bk[EPT];
        #pragma unroll
        for (int j = 0; j < EPT; ++j) {
            int e = base + j * 512 + t;       // coalesced
            bk[j] = -1;
            if (e < E) {
                int s = edge_src[e];
                int d = edge_dst[e];
                bk[j] = d >> 7;
                pk[j] = ((unsigned int)s << 7) | (unsigned int)(d & 127);
                atomicAdd(&lhist[bk[j]], 1);
            }
        }
        __syncthreads();
        for (int i = t; i < CB; i += 512) {
            lbase[i] = atomicAdd(&cursor[i], lhist[i]);
            lhist[i] = 0;
        }
        __syncthreads();
        #pragma unroll
        for (int j = 0; j < EPT; ++j) {
            if (bk[j] >= 0) {
                int r = atomicAdd(&lhist[bk[j]], 1);
                coarse[(size_t)bk[j] * CAP + lbase[bk[j]] + r] = pk[j];
            }
        }
    } else if (b < pa + 1563) {
        int i = (b - pa) * 512 + t;           // one float4 per thread
        if (i < N_NODES * DIM / 4) {
            float4 v = reinterpret_cast<const float4*>(x)[i];
            half4v h = { (_Float16)v.x, (_Float16)v.y, (_Float16)v.z, (_Float16)v.w };
            reinterpret_cast<half4v*>(xh)[i] = h;
        }
    } else {
        #pragma unroll
        for (int i = 0; i < 8; ++i) {         // W^T: wt[n*64+k] = W[k*64+n]
            int idx = t * 8 + i;
            int n = idx >> 6, k = idx & 63;
            wt[idx] = (_Float16)W[k * DIM + n];
        }
    }
}

// ---------------------------------------------------------------------------
// Fused bin + gather + project.  Grid 784; block b handles half
// half=(b>>3)&1 of bucket (b>>4)*8+(b&7) (sibling pair (b, b^8) -> same
// XCD under round-robin dispatch: bucket list fetched into one L2).
//  1. ONE scan pass: matching edges drop into per-node slot arrays
//     (sedges[bin*64+slot], slot via LDS int atomic).  No hist pass, no
//     prefix scan.  deg max ~35 << 64 cap.
//  2. 32 groups x 8 lanes, 2 nodes/group: 8 edges in flight, half8 fp16
//     gather, fp32 register accumulate, residual from xh (L2-hot), one
//     ds_write per row chunk into the stride-68 fp32 tile.
//  3. 4 waves x 16 nodes: fp32->f16 A-frags from the tile, B-frags from
//     W^T, 2x mfma_f32_16x16x32_f16 per N-tile, bias + /deg + ReLU -> out.
// ---------------------------------------------------------------------------
__global__ void __launch_bounds__(256) fused_kernel(
        const _Float16* __restrict__ xh,
        const _Float16* __restrict__ wt,
        const float* __restrict__ bias,
        const float* __restrict__ deg,
        const int* __restrict__ cursor,
        const unsigned int* __restrict__ coarse,
        float* __restrict__ out) {
    __shared__ int sedges[64 * BINCAP];    // 16 KB
    __shared__ float pl[64 * PLW];         // 17.4 KB
    __shared__ int cur[64];

    int t = threadIdx.x;
    int b = blockIdx.x;
    int bucket = (b >> 4) * 8 + (b & 7);   // pair (b, b^8) -> same bucket+XCD
    int half = (b >> 3) & 1;
    if (bucket >= CB) return;              // block-uniform early-out
    int nb = bucket * 128 + half * 64;     // global node base for this block
    int cnt = cursor[bucket];
    const unsigned int* cbk = coarse + (size_t)bucket * CAP;

    if (t < 64) cur[t] = 0;
    __syncthreads();

    // --- 1. one-pass binned scatter ---
    for (int i = t; i < cnt; i += 256) {
        unsigned int e = cbk[i];
        int loc = (int)(e & 127u);
        if ((loc >> 6) == half) {
            int bin = loc & 63;
            int p = atomicAdd(&cur[bin], 1);
            sedges[bin * BINCAP + p] = (int)(e >> 7);
        }
    }
    __syncthreads();

    // --- 2. gather: 32 groups of 8 lanes, 2 nodes per group, 8 in flight ---
    int g = t >> 3;          // group 0..31
    int c = t & 7;           // half8 chunk within the 64-half row
    #pragma unroll
    for (int pass = 0; pass < 2; ++pass) {
        int loc = g + pass * 32;
        int node = nb + loc;
        float acc[8];
        #pragma unroll
        for (int j = 0; j < 8; ++j) acc[j] = 0.f;
        const int* bp = &sedges[loc * BINCAP];
        int ct = cur[loc];                  // 0 for nodes >= N (no edges)
        int k = 0;
        for (; k + 8 <= ct; k += 8) {       // 8 edges in flight
            int sid[8];
            #pragma unroll
            for (int u = 0; u < 8; ++u) sid[u] = bp[k + u];
            half8 v[8];
            #pragma unroll
            for (int u = 0; u < 8; ++u)
                v[u] = *reinterpret_cast<const half8*>(xh + (size_t)sid[u] * DIM + c * 8);
            #pragma unroll
            for (int u = 0; u < 8; ++u) {
                #pragma unroll
                for (int j = 0; j < 8; ++j) acc[j] += (float)v[u][j];
            }
        }
        for (; k + 4 <= ct; k += 4) {       // 4-wide tail
            int sid[4];
            #pragma unroll
            for (int u = 0; u < 4; ++u) sid[u] = bp[k + u];
            half8 v[4];
            #pragma unroll
            for (int u = 0; u < 4; ++u)
                v[u] = *reinterpret_cast<const half8*>(xh + (size_t)sid[u] * DIM + c * 8);
            #pragma unroll
            for (int u = 0; u < 4; ++u) {
                #pragma unroll
                for (int j = 0; j < 8; ++j) acc[j] += (float)v[u][j];
            }
        }
        for (; k < ct; ++k) {
            int s0 = bp[k];
            half8 v0 = *reinterpret_cast<const half8*>(xh + (size_t)s0 * DIM + c * 8);
            #pragma unroll
            for (int j = 0; j < 8; ++j) acc[j] += (float)v0[j];
        }
        if (node < N_NODES) {
            half8 r = *reinterpret_cast<const half8*>(
                xh + (size_t)node * DIM + c * 8);
            float* p = &pl[loc * PLW + c * 8];
            #pragma unroll
            for (int j = 0; j < 8; ++j) p[j] = acc[j] + (float)r[j];
        }
    }
    __syncthreads();

    // --- 3. MFMA projection: wave wv handles nodes lbase..lbase+15 ---
    int wv = t >> 6;
    int lane = t & 63;
    int m = lane & 15;
    int q = lane >> 4;
    int lbase = wv * 16;

    const float* ap = &pl[(lbase + m) * PLW];
    half8 a0, a1;
    #pragma unroll
    for (int j = 0; j < 8; ++j) a0[j] = (_Float16)ap[q * 8 + j];
    #pragma unroll
    for (int j = 0; j < 8; ++j) a1[j] = (_Float16)ap[32 + q * 8 + j];

    floatx4 acc4[4];
    #pragma unroll
    for (int tt = 0; tt < 4; ++tt) {
        half8 b0 = *reinterpret_cast<const half8*>(wt + (size_t)(tt * 16 + m) * DIM + q * 8);
        half8 b1 = *reinterpret_cast<const half8*>(wt + (size_t)(tt * 16 + m) * DIM + q * 8 + 32);
        floatx4 cfrag = {0.f, 0.f, 0.f, 0.f};
        cfrag = __builtin_amdgcn_mfma_f32_16x16x32_f16(a0, b0, cfrag, 0, 0, 0);
        cfrag = __builtin_amdgcn_mfma_f32_16x16x32_f16(a1, b1, cfrag, 0, 0, 0);
        acc4[tt] = cfrag;
    }

    #pragma unroll
    for (int r = 0; r < 4; ++r) {
        int row = q * 4 + r;
        int node = nb + lbase + row;
        if (node < N_NODES) {
            float inv = 1.0f / deg[node];
            #pragma unroll
            for (int tt = 0; tt < 4; ++tt) {
                float v = (acc4[tt][r] + bias[tt * 16 + m]) * inv;
                out[(size_t)node * DIM + tt * 16 + m] = fmaxf(v, 0.f);
            }
        }
    }
}

extern "C" void kernel_launch(void* const* d_in, const int* in_sizes, int n_in,
                              void* d_out, int out_size, void* d_ws, size_t ws_size,
                              hipStream_t stream) {
    const float* x        = (const float*)d_in[0];
    const float* weight   = (const float*)d_in[1];
    const float* bias     = (const float*)d_in[2];
    const float* node_deg = (const float*)d_in[3];
    const int*   edge_src = (const int*)d_in[4];
    const int*   edge_dst = (const int*)d_in[5];
    float* out = (float*)d_out;
    const int E = in_sizes[4];

    char* ws = (char*)d_ws;
    int*          cursor = (int*)(ws + WS_CURSOR);
    unsigned int* coarse = (unsigned int*)(ws + WS_COARSE);
    _Float16*     xh     = (_Float16*)(ws + WS_XH);
    _Float16*     wt     = (_Float16*)(ws + WS_WT);

    hipMemsetAsync(cursor, 0, CB * sizeof(int), stream);

    int pa = (E + EB - 1) / EB;               // 131 partition blocks
    prep_kernel<<<pa + 1563 + 1, 512, 0, stream>>>(
        x, weight, edge_src, edge_dst, cursor, coarse, xh, wt, E, pa);

    fused_kernel<<<784, 256, 0, stream>>>(
        xh, wt, bias, node_deg, cursor, coarse, out);
}